// Round 3
// baseline (958.846 us; speedup 1.0000x reference)
//
#include <hip/hip_runtime.h>

#define IN_F 128
#define OUT_F 32
#define R_NODES 128          // dst nodes per bucket (7 bits)
#define BKT_CAP 4096         // >= 2048 expected + 45*sigma; overflow handled anyway
#define OVF_CAP 4096

// ---------------------------------------------------------------------------
// Stage 1: degrees + bucket partition (counting-sort edges by dst>>7).
// Bucket stores are cursor-sequential -> L2 write-combines into full lines
// (no 64B-line amplification, unlike the round-2 padded-CSR scatter).
// Packed entry: (src << 7) | (dst & 127).
// ---------------------------------------------------------------------------
__global__ void build_kernel(const int* __restrict__ src, const int* __restrict__ dst,
                             int* __restrict__ out_cnt, int* __restrict__ in_cnt,
                             int* __restrict__ cursors, unsigned* __restrict__ bkt,
                             int* __restrict__ ovf, int* __restrict__ ovf_cnt,
                             int n_edges) {
    int e = blockIdx.x * blockDim.x + threadIdx.x;
    if (e >= n_edges) return;
    int s = src[e], d = dst[e];
    atomicAdd(&out_cnt[s], 1);
    atomicAdd(&in_cnt[d], 1);
    int b = d >> 7;
    int pos = atomicAdd(&cursors[b], 1);
    if (pos < BKT_CAP) {
        bkt[(size_t)b * BKT_CAP + pos] = ((unsigned)s << 7) | (unsigned)(d & 127);
    } else {
        int o = atomicAdd(ovf_cnt, 1);
        if (o < OVF_CAP) { ovf[2 * o] = s; ovf[2 * o + 1] = d; }
    }
}

// ---------------------------------------------------------------------------
// Stage 2: tmp = (feat * outdeg^-1/2) @ W.  4 rows x 4 cols per thread,
// float4 global loads, W in LDS (float4 broadcast reads, conflict-free).
// ---------------------------------------------------------------------------
__global__ __launch_bounds__(256) void linear_kernel(const float* __restrict__ feat,
                                                     const float* __restrict__ weight,
                                                     const int* __restrict__ out_cnt,
                                                     float* __restrict__ tmp, int n_nodes) {
    __shared__ float w[IN_F * OUT_F];
    {
        const float4* wg = (const float4*)weight;
        float4* wsh = (float4*)w;
        for (int i = threadIdx.x; i < IN_F * OUT_F / 4; i += 256) wsh[i] = wg[i];
    }
    __syncthreads();

    int q  = threadIdx.x >> 3;   // 0..31
    int cg = threadIdx.x & 7;    // 0..7
    int row0 = blockIdx.x * 128 + q * 4;
    if (row0 >= n_nodes) return;
    int rmax = n_nodes - row0;
    if (rmax > 4) rmax = 4;

    const float4* feat4 = (const float4*)feat;
    float4 acc[4];
#pragma unroll
    for (int r = 0; r < 4; ++r) acc[r] = make_float4(0.f, 0.f, 0.f, 0.f);

    for (int k4 = 0; k4 < IN_F / 4; ++k4) {
        float4 wv0 = *(const float4*)&w[(4 * k4 + 0) * OUT_F + 4 * cg];
        float4 wv1 = *(const float4*)&w[(4 * k4 + 1) * OUT_F + 4 * cg];
        float4 wv2 = *(const float4*)&w[(4 * k4 + 2) * OUT_F + 4 * cg];
        float4 wv3 = *(const float4*)&w[(4 * k4 + 3) * OUT_F + 4 * cg];
#pragma unroll
        for (int r = 0; r < 4; ++r) {
            int rr = (r < rmax) ? r : 0;
            float4 f = feat4[(size_t)(row0 + rr) * (IN_F / 4) + k4];
            acc[r].x += f.x * wv0.x + f.y * wv1.x + f.z * wv2.x + f.w * wv3.x;
            acc[r].y += f.x * wv0.y + f.y * wv1.y + f.z * wv2.y + f.w * wv3.y;
            acc[r].z += f.x * wv0.z + f.y * wv1.z + f.z * wv2.z + f.w * wv3.z;
            acc[r].w += f.x * wv0.w + f.y * wv1.w + f.z * wv2.w + f.w * wv3.w;
        }
    }

    float4* tmp4 = (float4*)tmp;
#pragma unroll
    for (int r = 0; r < 4; ++r) {
        if (r < rmax) {
            float sc = rsqrtf(fmaxf((float)out_cnt[row0 + r], 1.0f));
            float4 o = acc[r];
            o.x *= sc; o.y *= sc; o.z *= sc; o.w *= sc;
            tmp4[(size_t)(row0 + r) * (OUT_F / 4) + cg] = o;
        }
    }
}

// ---------------------------------------------------------------------------
// Stage 3: one block per bucket of 128 dst nodes. LDS accumulator
// acc[128][32] (16 KB -> 8 blocks/CU). Each 32-lane group takes one edge:
// lanes load tmp[src][0..31] (coalesced 128B row) and ds_add_f32 into
// acc[local][0..31] (banks 0..31, conflict-free). Scaled coalesced epilogue.
// ---------------------------------------------------------------------------
__global__ __launch_bounds__(256) void bucket_gather(const unsigned* __restrict__ bkt,
                                                     const int* __restrict__ cursors,
                                                     const int* __restrict__ in_cnt,
                                                     const float* __restrict__ tmp,
                                                     float* __restrict__ out, int n_nodes) {
    __shared__ float acc[R_NODES * OUT_F];  // 16 KB
    int b = blockIdx.x;
    int n0 = b * R_NODES;

    {
        float4* a4 = (float4*)acc;
        for (int i = threadIdx.x; i < R_NODES * OUT_F / 4; i += 256)
            a4[i] = make_float4(0.f, 0.f, 0.f, 0.f);
    }
    __syncthreads();

    int ecnt = min(cursors[b], BKT_CAP);
    const unsigned* ebase = bkt + (size_t)b * BKT_CAP;
    int g = threadIdx.x >> 5;   // edge-group 0..7
    int c = threadIdx.x & 31;   // column

    for (int e = g; e < ecnt; e += 8) {
        unsigned v = ebase[e];              // broadcast within group (L1 hit)
        int s = (int)(v >> 7);
        int local = (int)(v & 127);
        float val = tmp[(size_t)s * OUT_F + c];
        atomicAdd(&acc[local * OUT_F + c], val);
    }
    __syncthreads();

    int nmax = min(R_NODES, n_nodes - n0);
    for (int i = threadIdx.x; i < nmax * OUT_F; i += 256) {
        int node = n0 + (i >> 5);
        float sc = rsqrtf(fmaxf((float)in_cnt[node], 1.0f));
        out[(size_t)n0 * OUT_F + i] = acc[i] * sc;
    }
}

// ---------------------------------------------------------------------------
// Stage 3b: overflow edges (bucket cap exceeded) — expected 0; correctness.
// ---------------------------------------------------------------------------
__global__ void ovf_kernel(const int* __restrict__ ovf, const int* __restrict__ ovf_cnt,
                           const int* __restrict__ in_cnt, const float* __restrict__ tmp,
                           float* __restrict__ out) {
    int t = blockIdx.x * blockDim.x + threadIdx.x;
    int e = t >> 5, c = t & 31;
    int n = min(*ovf_cnt, OVF_CAP);
    if (e < n) {
        int s = ovf[2 * e], d = ovf[2 * e + 1];
        float scale = rsqrtf(fmaxf((float)in_cnt[d], 1.0f));
        atomicAdd(&out[(size_t)d * OUT_F + c], tmp[(size_t)s * OUT_F + c] * scale);
    }
}

// ---------------------------------------------------------------------------
// Fallback (ws too small): atomic scatter path.
// ---------------------------------------------------------------------------
__global__ void scatter_kernel(const int* __restrict__ src, const int* __restrict__ dst,
                               const float* __restrict__ tmp, float* __restrict__ out,
                               int n_edges) {
    long long t = (long long)blockIdx.x * blockDim.x + threadIdx.x;
    int e = (int)(t >> 5);
    int c = (int)(t & (OUT_F - 1));
    if (e < n_edges) {
        atomicAdd(&out[(size_t)dst[e] * OUT_F + c], tmp[(size_t)src[e] * OUT_F + c]);
    }
}

__global__ void finalize_kernel(float* __restrict__ out, const int* __restrict__ in_cnt,
                                int n_total) {
    int t = blockIdx.x * blockDim.x + threadIdx.x;
    if (t < n_total) {
        out[t] *= rsqrtf(fmaxf((float)in_cnt[t >> 5], 1.0f));
    }
}

__global__ void degree_kernel(const int* __restrict__ src, const int* __restrict__ dst,
                              int* __restrict__ out_cnt, int* __restrict__ in_cnt,
                              int n_edges) {
    int i = blockIdx.x * blockDim.x + threadIdx.x;
    if (i < n_edges) {
        atomicAdd(&out_cnt[src[i]], 1);
        atomicAdd(&in_cnt[dst[i]], 1);
    }
}

extern "C" void kernel_launch(void* const* d_in, const int* in_sizes, int n_in,
                              void* d_out, int out_size, void* d_ws, size_t ws_size,
                              hipStream_t stream) {
    const float* feat   = (const float*)d_in[0];
    const int*   src    = (const int*)d_in[1];
    const int*   dst    = (const int*)d_in[2];
    const float* weight = (const float*)d_in[3];
    float*       out    = (float*)d_out;

    int n_nodes = in_sizes[0] / IN_F;   // 100000
    int n_edges = in_sizes[1];          // 1600000
    int n_buckets = (n_nodes + R_NODES - 1) / R_NODES;  // 782

    // ws layout: [out_cnt n][in_cnt n][cursors nb][ovf_cnt 8][ovf 2*CAP][bkt nb*BKT_CAP][tmp n*32]
    int*      out_cnt = (int*)d_ws;
    int*      in_cnt  = out_cnt + n_nodes;
    int*      cursors = in_cnt + n_nodes;
    int*      ovf_cnt = cursors + n_buckets;
    int*      ovf     = ovf_cnt + 8;
    unsigned* bkt     = (unsigned*)(ovf + 2 * OVF_CAP);
    float*    tmp     = (float*)(bkt + (size_t)n_buckets * BKT_CAP);
    size_t    needed  = (char*)(tmp + (size_t)n_nodes * OUT_F) - (char*)d_ws;

    if (ws_size >= needed) {
        hipMemsetAsync(out_cnt, 0, ((size_t)2 * n_nodes + n_buckets + 8) * sizeof(int), stream);
        build_kernel<<<(n_edges + 255) / 256, 256, 0, stream>>>(
            src, dst, out_cnt, in_cnt, cursors, bkt, ovf, ovf_cnt, n_edges);
        linear_kernel<<<(n_nodes + 127) / 128, 256, 0, stream>>>(
            feat, weight, out_cnt, tmp, n_nodes);
        bucket_gather<<<n_buckets, 256, 0, stream>>>(
            bkt, cursors, in_cnt, tmp, out, n_nodes);
        ovf_kernel<<<OVF_CAP * 32 / 256, 256, 0, stream>>>(ovf, ovf_cnt, in_cnt, tmp, out);
    } else {
        // fallback: atomic scatter
        float* tmp_fb = (float*)(ovf + 2 * OVF_CAP);
        hipMemsetAsync(out_cnt, 0, ((size_t)2 * n_nodes + n_buckets + 8) * sizeof(int), stream);
        hipMemsetAsync(d_out, 0, (size_t)out_size * sizeof(float), stream);
        degree_kernel<<<(n_edges + 255) / 256, 256, 0, stream>>>(src, dst, out_cnt, in_cnt, n_edges);
        linear_kernel<<<(n_nodes + 127) / 128, 256, 0, stream>>>(feat, weight, out_cnt, tmp_fb, n_nodes);
        long long st = (long long)n_edges * OUT_F;
        scatter_kernel<<<(int)((st + 255) / 256), 256, 0, stream>>>(src, dst, tmp_fb, out, n_edges);
        finalize_kernel<<<(n_nodes * OUT_F + 255) / 256, 256, 0, stream>>>(out, in_cnt, n_nodes * OUT_F);
    }
}

// Round 4
// 611.023 us; speedup vs baseline: 1.5692x; 1.5692x over previous
//
#include <hip/hip_runtime.h>

#define IN_F 128
#define OUT_F 32
#define R_NODES 128          // dst nodes per bucket (7 bits)
#define BKT_CAP 4096         // Poisson(2046)+45sigma; overflow handled anyway
#define OVF_CAP 4096
#define EPB 8192             // edges per build block
#define MAXNB 1024           // max buckets => n_nodes <= 131072

// ---------------------------------------------------------------------------
// Stage 1: degrees + bucket partition via BLOCK-LOCAL counting sort.
// Round-3 lesson: grid-wide scattered 4B stores amplify ~25x (cross-XCD
// partial-line writebacks) and 782-address cursor atomics serialize ~2000
// deep. Fix: per-block LDS sort by bin, ONE cursor atomic per (block,bin),
// then chunked flush (~10.5 entries/chunk, consecutive addresses -> full
// lines from one wave on one XCD).
// ---------------------------------------------------------------------------
__global__ __launch_bounds__(256) void build_kernel(
    const int* __restrict__ src, const int* __restrict__ dst,
    int* __restrict__ out_cnt, int* __restrict__ in_cnt,
    int* __restrict__ gcur, unsigned* __restrict__ bkt,
    int* __restrict__ ovf, int* __restrict__ ovf_cnt,
    int n_edges) {

    __shared__ unsigned sorted[EPB];        // 32 KB
    __shared__ unsigned short binof[EPB];   // 16 KB
    __shared__ int hist[MAXNB];             // counts, then insertion cursor
    __shared__ int lbase[MAXNB];
    __shared__ int gbase[MAXNB];
    __shared__ int wsum[4];

    int tid = threadIdx.x;
    int e0 = blockIdx.x * EPB;
    int ecnt = min(EPB, n_edges - e0);

    int b0 = tid * 4;                       // 4 bins per thread
#pragma unroll
    for (int r = 0; r < 4; ++r) hist[b0 + r] = 0;
    __syncthreads();

    // pass 1: degree atomics + bin histogram
    for (int k = tid; k < ecnt; k += 256) {
        int e = e0 + k;
        int s = src[e], d = dst[e];
        atomicAdd(&out_cnt[s], 1);
        atomicAdd(&in_cnt[d], 1);
        atomicAdd(&hist[d >> 7], 1);
    }
    __syncthreads();

    // block-wide exclusive scan of hist -> lbase; reserve global chunks
    int c[4]; int tsum = 0;
#pragma unroll
    for (int r = 0; r < 4; ++r) { c[r] = hist[b0 + r]; tsum += c[r]; }
    int lane = tid & 63, wid = tid >> 6;
    int scan = tsum;
    for (int off = 1; off < 64; off <<= 1) {
        int v = __shfl_up(scan, off, 64);
        if (lane >= off) scan += v;
    }
    if (lane == 63) wsum[wid] = scan;
    __syncthreads();
    int woff = 0;
    for (int w = 0; w < wid; ++w) woff += wsum[w];
    int run = woff + scan - tsum;           // exclusive prefix of this thread's bins
#pragma unroll
    for (int r = 0; r < 4; ++r) {
        lbase[b0 + r] = run;
        hist[b0 + r]  = run;                // becomes the insertion cursor
        if (c[r] > 0) gbase[b0 + r] = atomicAdd(&gcur[b0 + r], c[r]);
        run += c[r];
    }
    __syncthreads();

    // pass 2: local counting-sort into LDS (re-read edges, L2-hot)
    for (int k = tid; k < ecnt; k += 256) {
        int e = e0 + k;
        int s = src[e], d = dst[e];
        int bin = d >> 7;
        int idx = atomicAdd(&hist[bin], 1);
        sorted[idx] = ((unsigned)s << 7) | (unsigned)(d & 127);
        binof[idx]  = (unsigned short)bin;
    }
    __syncthreads();

    // pass 3: chunked, mostly-coalesced flush
    for (int i = tid; i < ecnt; i += 256) {
        unsigned v = sorted[i];
        int bin = binof[i];
        int gpos = gbase[bin] + (i - lbase[bin]);
        if (gpos < BKT_CAP) {
            bkt[(size_t)bin * BKT_CAP + gpos] = v;
        } else {
            int o = atomicAdd(ovf_cnt, 1);
            if (o < OVF_CAP) {
                ovf[2 * o]     = (int)(v >> 7);
                ovf[2 * o + 1] = bin * R_NODES + (int)(v & 127);
            }
        }
    }
}

// ---------------------------------------------------------------------------
// Stage 2: tmp = (feat * outdeg^-1/2) @ W.  4 rows x 4 cols per thread,
// float4 global loads, W in LDS (float4 broadcast reads, conflict-free).
// ---------------------------------------------------------------------------
__global__ __launch_bounds__(256) void linear_kernel(const float* __restrict__ feat,
                                                     const float* __restrict__ weight,
                                                     const int* __restrict__ out_cnt,
                                                     float* __restrict__ tmp, int n_nodes) {
    __shared__ float w[IN_F * OUT_F];
    {
        const float4* wg = (const float4*)weight;
        float4* wsh = (float4*)w;
        for (int i = threadIdx.x; i < IN_F * OUT_F / 4; i += 256) wsh[i] = wg[i];
    }
    __syncthreads();

    int q  = threadIdx.x >> 3;
    int cg = threadIdx.x & 7;
    int row0 = blockIdx.x * 128 + q * 4;
    if (row0 >= n_nodes) return;
    int rmax = n_nodes - row0;
    if (rmax > 4) rmax = 4;

    const float4* feat4 = (const float4*)feat;
    float4 acc[4];
#pragma unroll
    for (int r = 0; r < 4; ++r) acc[r] = make_float4(0.f, 0.f, 0.f, 0.f);

    for (int k4 = 0; k4 < IN_F / 4; ++k4) {
        float4 wv0 = *(const float4*)&w[(4 * k4 + 0) * OUT_F + 4 * cg];
        float4 wv1 = *(const float4*)&w[(4 * k4 + 1) * OUT_F + 4 * cg];
        float4 wv2 = *(const float4*)&w[(4 * k4 + 2) * OUT_F + 4 * cg];
        float4 wv3 = *(const float4*)&w[(4 * k4 + 3) * OUT_F + 4 * cg];
#pragma unroll
        for (int r = 0; r < 4; ++r) {
            int rr = (r < rmax) ? r : 0;
            float4 f = feat4[(size_t)(row0 + rr) * (IN_F / 4) + k4];
            acc[r].x += f.x * wv0.x + f.y * wv1.x + f.z * wv2.x + f.w * wv3.x;
            acc[r].y += f.x * wv0.y + f.y * wv1.y + f.z * wv2.y + f.w * wv3.y;
            acc[r].z += f.x * wv0.z + f.y * wv1.z + f.z * wv2.z + f.w * wv3.z;
            acc[r].w += f.x * wv0.w + f.y * wv1.w + f.z * wv2.w + f.w * wv3.w;
        }
    }

    float4* tmp4 = (float4*)tmp;
#pragma unroll
    for (int r = 0; r < 4; ++r) {
        if (r < rmax) {
            float sc = rsqrtf(fmaxf((float)out_cnt[row0 + r], 1.0f));
            float4 o = acc[r];
            o.x *= sc; o.y *= sc; o.z *= sc; o.w *= sc;
            tmp4[(size_t)(row0 + r) * (OUT_F / 4) + cg] = o;
        }
    }
}

// ---------------------------------------------------------------------------
// Stage 3: one block per 128-node bucket. 16 KB LDS accumulator, LDS float
// atomics (bank-conflict-free: lanes 0..31 hit banks 0..31), scaled
// coalesced epilogue. Proven correct in round 3.
// ---------------------------------------------------------------------------
__global__ __launch_bounds__(256) void bucket_gather(const unsigned* __restrict__ bkt,
                                                     const int* __restrict__ gcur,
                                                     const int* __restrict__ in_cnt,
                                                     const float* __restrict__ tmp,
                                                     float* __restrict__ out, int n_nodes) {
    __shared__ float acc[R_NODES * OUT_F];  // 16 KB
    int b = blockIdx.x;
    int n0 = b * R_NODES;

    {
        float4* a4 = (float4*)acc;
        for (int i = threadIdx.x; i < R_NODES * OUT_F / 4; i += 256)
            a4[i] = make_float4(0.f, 0.f, 0.f, 0.f);
    }
    __syncthreads();

    int ecnt = min(gcur[b], BKT_CAP);
    const unsigned* ebase = bkt + (size_t)b * BKT_CAP;
    int g = threadIdx.x >> 5;
    int c = threadIdx.x & 31;

    for (int e = g; e < ecnt; e += 8) {
        unsigned v = ebase[e];
        int s = (int)(v >> 7);
        int local = (int)(v & 127);
        float val = tmp[(size_t)s * OUT_F + c];
        atomicAdd(&acc[local * OUT_F + c], val);
    }
    __syncthreads();

    int nmax = min(R_NODES, n_nodes - n0);
    for (int i = threadIdx.x; i < nmax * OUT_F; i += 256) {
        int node = n0 + (i >> 5);
        float sc = rsqrtf(fmaxf((float)in_cnt[node], 1.0f));
        out[(size_t)n0 * OUT_F + i] = acc[i] * sc;
    }
}

// ---------------------------------------------------------------------------
// Stage 3b: overflow edges (bucket cap exceeded) — expected 0; correctness.
// ---------------------------------------------------------------------------
__global__ void ovf_kernel(const int* __restrict__ ovf, const int* __restrict__ ovf_cnt,
                           const int* __restrict__ in_cnt, const float* __restrict__ tmp,
                           float* __restrict__ out) {
    int t = blockIdx.x * blockDim.x + threadIdx.x;
    int e = t >> 5, c = t & 31;
    int n = min(*ovf_cnt, OVF_CAP);
    if (e < n) {
        int s = ovf[2 * e], d = ovf[2 * e + 1];
        float scale = rsqrtf(fmaxf((float)in_cnt[d], 1.0f));
        atomicAdd(&out[(size_t)d * OUT_F + c], tmp[(size_t)s * OUT_F + c] * scale);
    }
}

// ---------------------------------------------------------------------------
// Fallback (ws too small): round-1 atomic scatter path.
// ---------------------------------------------------------------------------
__global__ void scatter_kernel(const int* __restrict__ src, const int* __restrict__ dst,
                               const float* __restrict__ tmp, float* __restrict__ out,
                               int n_edges) {
    long long t = (long long)blockIdx.x * blockDim.x + threadIdx.x;
    int e = (int)(t >> 5);
    int c = (int)(t & (OUT_F - 1));
    if (e < n_edges) {
        atomicAdd(&out[(size_t)dst[e] * OUT_F + c], tmp[(size_t)src[e] * OUT_F + c]);
    }
}

__global__ void finalize_kernel(float* __restrict__ out, const int* __restrict__ in_cnt,
                                int n_total) {
    int t = blockIdx.x * blockDim.x + threadIdx.x;
    if (t < n_total) {
        out[t] *= rsqrtf(fmaxf((float)in_cnt[t >> 5], 1.0f));
    }
}

__global__ void degree_kernel(const int* __restrict__ src, const int* __restrict__ dst,
                              int* __restrict__ out_cnt, int* __restrict__ in_cnt,
                              int n_edges) {
    int i = blockIdx.x * blockDim.x + threadIdx.x;
    if (i < n_edges) {
        atomicAdd(&out_cnt[src[i]], 1);
        atomicAdd(&in_cnt[dst[i]], 1);
    }
}

extern "C" void kernel_launch(void* const* d_in, const int* in_sizes, int n_in,
                              void* d_out, int out_size, void* d_ws, size_t ws_size,
                              hipStream_t stream) {
    const float* feat   = (const float*)d_in[0];
    const int*   src    = (const int*)d_in[1];
    const int*   dst    = (const int*)d_in[2];
    const float* weight = (const float*)d_in[3];
    float*       out    = (float*)d_out;

    int n_nodes = in_sizes[0] / IN_F;   // 100000
    int n_edges = in_sizes[1];          // 1600000
    int n_buckets = (n_nodes + R_NODES - 1) / R_NODES;  // 782 (<= MAXNB)

    // ws layout: [out_cnt n][in_cnt n][gcur MAXNB][ovf_cnt 8][ovf 2*CAP][bkt][tmp]
    int*      out_cnt = (int*)d_ws;
    int*      in_cnt  = out_cnt + n_nodes;
    int*      gcur    = in_cnt + n_nodes;
    int*      ovf_cnt = gcur + MAXNB;
    int*      ovf     = ovf_cnt + 8;
    unsigned* bkt     = (unsigned*)(ovf + 2 * OVF_CAP);
    float*    tmp     = (float*)(bkt + (size_t)n_buckets * BKT_CAP);
    size_t    needed  = (char*)(tmp + (size_t)n_nodes * OUT_F) - (char*)d_ws;

    if (ws_size >= needed && n_buckets <= MAXNB) {
        hipMemsetAsync(out_cnt, 0, ((size_t)2 * n_nodes + MAXNB + 8) * sizeof(int), stream);
        build_kernel<<<(n_edges + EPB - 1) / EPB, 256, 0, stream>>>(
            src, dst, out_cnt, in_cnt, gcur, bkt, ovf, ovf_cnt, n_edges);
        linear_kernel<<<(n_nodes + 127) / 128, 256, 0, stream>>>(
            feat, weight, out_cnt, tmp, n_nodes);
        bucket_gather<<<n_buckets, 256, 0, stream>>>(
            bkt, gcur, in_cnt, tmp, out, n_nodes);
        ovf_kernel<<<OVF_CAP * 32 / 256, 256, 0, stream>>>(ovf, ovf_cnt, in_cnt, tmp, out);
    } else {
        // fallback: atomic scatter
        float* tmp_fb = (float*)(ovf + 2 * OVF_CAP);
        hipMemsetAsync(out_cnt, 0, ((size_t)2 * n_nodes + MAXNB + 8) * sizeof(int), stream);
        hipMemsetAsync(d_out, 0, (size_t)out_size * sizeof(float), stream);
        degree_kernel<<<(n_edges + 255) / 256, 256, 0, stream>>>(src, dst, out_cnt, in_cnt, n_edges);
        linear_kernel<<<(n_nodes + 127) / 128, 256, 0, stream>>>(feat, weight, out_cnt, tmp_fb, n_nodes);
        long long st = (long long)n_edges * OUT_F;
        scatter_kernel<<<(int)((st + 255) / 256), 256, 0, stream>>>(src, dst, tmp_fb, out, n_edges);
        finalize_kernel<<<(n_nodes * OUT_F + 255) / 256, 256, 0, stream>>>(out, in_cnt, n_nodes * OUT_F);
    }
}

// Round 5
// 543.444 us; speedup vs baseline: 1.7644x; 1.1244x over previous
//
#include <hip/hip_runtime.h>

#define IN_F 128
#define OUT_F 32
#define R_NODES 128          // dst nodes per bucket (7 bits)
#define BKT_CAP 4096         // Poisson(2046)+45sigma; overflow handled anyway
#define OVF_CAP 4096
#define EPB 8192             // edges per build block
#define MAXNB 1024           // max buckets => n_nodes <= 131072

// ---------------------------------------------------------------------------
// Stage 1: degrees + bucket partition via BLOCK-LOCAL counting sort.
// (round-3 lesson: never grid-scatter 4B grains; chunked flush only.)
// in_cnt here counts ONLY overflow edges (deg>BKT_CAP, ~never); the main
// in-degree is counted in bucket_gather from the bucket entries themselves.
// ---------------------------------------------------------------------------
__global__ __launch_bounds__(256) void build_kernel(
    const int* __restrict__ src, const int* __restrict__ dst,
    int* __restrict__ out_cnt, int* __restrict__ in_cnt,
    int* __restrict__ gcur, unsigned* __restrict__ bkt,
    int* __restrict__ ovf, int* __restrict__ ovf_cnt,
    int n_edges) {

    __shared__ unsigned sorted[EPB];        // 32 KB
    __shared__ unsigned short binof[EPB];   // 16 KB
    __shared__ int hist[MAXNB];
    __shared__ int lbase[MAXNB];
    __shared__ int gbase[MAXNB];
    __shared__ int wsum[4];

    int tid = threadIdx.x;
    int e0 = blockIdx.x * EPB;
    int ecnt = min(EPB, n_edges - e0);

    int b0 = tid * 4;
#pragma unroll
    for (int r = 0; r < 4; ++r) hist[b0 + r] = 0;
    __syncthreads();

    // pass 1: src-degree atomics + bin histogram
    for (int k = tid; k < ecnt; k += 256) {
        int e = e0 + k;
        int s = src[e], d = dst[e];
        atomicAdd(&out_cnt[s], 1);
        atomicAdd(&hist[d >> 7], 1);
    }
    __syncthreads();

    // block-wide exclusive scan of hist -> lbase; reserve global chunks
    int c[4]; int tsum = 0;
#pragma unroll
    for (int r = 0; r < 4; ++r) { c[r] = hist[b0 + r]; tsum += c[r]; }
    int lane = tid & 63, wid = tid >> 6;
    int scan = tsum;
    for (int off = 1; off < 64; off <<= 1) {
        int v = __shfl_up(scan, off, 64);
        if (lane >= off) scan += v;
    }
    if (lane == 63) wsum[wid] = scan;
    __syncthreads();
    int woff = 0;
    for (int w = 0; w < wid; ++w) woff += wsum[w];
    int run = woff + scan - tsum;
#pragma unroll
    for (int r = 0; r < 4; ++r) {
        lbase[b0 + r] = run;
        hist[b0 + r]  = run;                // becomes insertion cursor
        if (c[r] > 0) gbase[b0 + r] = atomicAdd(&gcur[b0 + r], c[r]);
        run += c[r];
    }
    __syncthreads();

    // pass 2: local counting-sort into LDS (edges re-read, L2-hot)
    for (int k = tid; k < ecnt; k += 256) {
        int e = e0 + k;
        int s = src[e], d = dst[e];
        int bin = d >> 7;
        int idx = atomicAdd(&hist[bin], 1);
        sorted[idx] = ((unsigned)s << 7) | (unsigned)(d & 127);
        binof[idx]  = (unsigned short)bin;
    }
    __syncthreads();

    // pass 3: chunked, mostly-coalesced flush
    for (int i = tid; i < ecnt; i += 256) {
        unsigned v = sorted[i];
        int bin = binof[i];
        int gpos = gbase[bin] + (i - lbase[bin]);
        if (gpos < BKT_CAP) {
            bkt[(size_t)bin * BKT_CAP + gpos] = v;
        } else {
            int d = bin * R_NODES + (int)(v & 127);
            atomicAdd(&in_cnt[d], 1);       // overflow-only in-degree
            int o = atomicAdd(ovf_cnt, 1);
            if (o < OVF_CAP) {
                ovf[2 * o]     = (int)(v >> 7);
                ovf[2 * o + 1] = d;
            }
        }
    }
}

// ---------------------------------------------------------------------------
// Stage 2: tmp = (feat * outdeg^-1/2) @ W.  4 rows x 4 cols per thread.
// ---------------------------------------------------------------------------
__global__ __launch_bounds__(256) void linear_kernel(const float* __restrict__ feat,
                                                     const float* __restrict__ weight,
                                                     const int* __restrict__ out_cnt,
                                                     float* __restrict__ tmp, int n_nodes) {
    __shared__ float w[IN_F * OUT_F];
    {
        const float4* wg = (const float4*)weight;
        float4* wsh = (float4*)w;
        for (int i = threadIdx.x; i < IN_F * OUT_F / 4; i += 256) wsh[i] = wg[i];
    }
    __syncthreads();

    int q  = threadIdx.x >> 3;
    int cg = threadIdx.x & 7;
    int row0 = blockIdx.x * 128 + q * 4;
    if (row0 >= n_nodes) return;
    int rmax = n_nodes - row0;
    if (rmax > 4) rmax = 4;

    const float4* feat4 = (const float4*)feat;
    float4 acc[4];
#pragma unroll
    for (int r = 0; r < 4; ++r) acc[r] = make_float4(0.f, 0.f, 0.f, 0.f);

    for (int k4 = 0; k4 < IN_F / 4; ++k4) {
        float4 wv0 = *(const float4*)&w[(4 * k4 + 0) * OUT_F + 4 * cg];
        float4 wv1 = *(const float4*)&w[(4 * k4 + 1) * OUT_F + 4 * cg];
        float4 wv2 = *(const float4*)&w[(4 * k4 + 2) * OUT_F + 4 * cg];
        float4 wv3 = *(const float4*)&w[(4 * k4 + 3) * OUT_F + 4 * cg];
#pragma unroll
        for (int r = 0; r < 4; ++r) {
            int rr = (r < rmax) ? r : 0;
            float4 f = feat4[(size_t)(row0 + rr) * (IN_F / 4) + k4];
            acc[r].x += f.x * wv0.x + f.y * wv1.x + f.z * wv2.x + f.w * wv3.x;
            acc[r].y += f.x * wv0.y + f.y * wv1.y + f.z * wv2.y + f.w * wv3.y;
            acc[r].z += f.x * wv0.z + f.y * wv1.z + f.z * wv2.z + f.w * wv3.z;
            acc[r].w += f.x * wv0.w + f.y * wv1.w + f.z * wv2.w + f.w * wv3.w;
        }
    }

    float4* tmp4 = (float4*)tmp;
#pragma unroll
    for (int r = 0; r < 4; ++r) {
        if (r < rmax) {
            float sc = rsqrtf(fmaxf((float)out_cnt[row0 + r], 1.0f));
            float4 o = acc[r];
            o.x *= sc; o.y *= sc; o.z *= sc; o.w *= sc;
            tmp4[(size_t)(row0 + r) * (OUT_F / 4) + cg] = o;
        }
    }
}

// ---------------------------------------------------------------------------
// Stage 3: one 1024-thread block per 128-node bucket. 32 edge-groups of 32
// lanes; 4-way ILP batching (4 independent entry+row loads in flight before
// the LDS atomics) -> ~256 outstanding loads/CU at 2 blocks/CU (32 waves).
// In-degree counted from bucket entries (lane 0 of each group, LDS atomic);
// total degree = lcnt + overflow in_cnt; deg[] exported for ovf_kernel.
// ---------------------------------------------------------------------------
__global__ __launch_bounds__(1024) void bucket_gather(const unsigned* __restrict__ bkt,
                                                      const int* __restrict__ gcur,
                                                      const int* __restrict__ in_cnt,
                                                      const float* __restrict__ tmp,
                                                      float* __restrict__ out,
                                                      int* __restrict__ deg, int n_nodes) {
    __shared__ float acc[R_NODES * OUT_F];  // 16 KB
    __shared__ int lcnt[R_NODES];
    int b = blockIdx.x;
    int n0 = b * R_NODES;
    int tid = threadIdx.x;

    {
        float4* a4 = (float4*)acc;
        for (int i = tid; i < R_NODES * OUT_F / 4; i += 1024)
            a4[i] = make_float4(0.f, 0.f, 0.f, 0.f);
        if (tid < R_NODES) lcnt[tid] = 0;
    }
    __syncthreads();

    int ecnt = min(gcur[b], BKT_CAP);
    const unsigned* ebase = bkt + (size_t)b * BKT_CAP;
    int g = tid >> 5;    // edge-group 0..31
    int c = tid & 31;    // column

    for (int e = g; e < ecnt; e += 128) {
        unsigned v[4]; float val[4]; int l[4]; bool ok[4];
#pragma unroll
        for (int k = 0; k < 4; ++k) {
            int ee = e + 32 * k;
            ok[k] = ee < ecnt;
            v[k] = ok[k] ? ebase[ee] : 0u;
        }
#pragma unroll
        for (int k = 0; k < 4; ++k) {
            l[k] = (int)(v[k] & 127u);
            val[k] = ok[k] ? tmp[(size_t)(v[k] >> 7) * OUT_F + c] : 0.f;
        }
#pragma unroll
        for (int k = 0; k < 4; ++k) {
            if (ok[k]) {
                atomicAdd(&acc[l[k] * OUT_F + c], val[k]);
                if (c == 0) atomicAdd(&lcnt[l[k]], 1);
            }
        }
    }
    __syncthreads();

    int nmax = min(R_NODES, n_nodes - n0);
    for (int i = tid; i < nmax * OUT_F; i += 1024) {
        int ln = i >> 5;
        int node = n0 + ln;
        int d = lcnt[ln] + in_cnt[node];    // in_cnt holds overflow-only counts
        if ((i & 31) == 0) deg[node] = d;
        float sc = rsqrtf(fmaxf((float)d, 1.0f));
        out[(size_t)n0 * OUT_F + i] = acc[i] * sc;
    }
}

// ---------------------------------------------------------------------------
// Stage 3b: overflow edges (bucket cap exceeded) — expected 0; correctness.
// Uses deg[] (total in-degree) exported by bucket_gather.
// ---------------------------------------------------------------------------
__global__ void ovf_kernel(const int* __restrict__ ovf, const int* __restrict__ ovf_cnt,
                           const int* __restrict__ deg, const float* __restrict__ tmp,
                           float* __restrict__ out) {
    int t = blockIdx.x * blockDim.x + threadIdx.x;
    int e = t >> 5, c = t & 31;
    int n = min(*ovf_cnt, OVF_CAP);
    if (e < n) {
        int s = ovf[2 * e], d = ovf[2 * e + 1];
        float scale = rsqrtf(fmaxf((float)deg[d], 1.0f));
        atomicAdd(&out[(size_t)d * OUT_F + c], tmp[(size_t)s * OUT_F + c] * scale);
    }
}

// ---------------------------------------------------------------------------
// Fallback (ws too small): round-1 atomic scatter path.
// ---------------------------------------------------------------------------
__global__ void scatter_kernel(const int* __restrict__ src, const int* __restrict__ dst,
                               const float* __restrict__ tmp, float* __restrict__ out,
                               int n_edges) {
    long long t = (long long)blockIdx.x * blockDim.x + threadIdx.x;
    int e = (int)(t >> 5);
    int c = (int)(t & (OUT_F - 1));
    if (e < n_edges) {
        atomicAdd(&out[(size_t)dst[e] * OUT_F + c], tmp[(size_t)src[e] * OUT_F + c]);
    }
}

__global__ void finalize_kernel(float* __restrict__ out, const int* __restrict__ in_cnt,
                                int n_total) {
    int t = blockIdx.x * blockDim.x + threadIdx.x;
    if (t < n_total) {
        out[t] *= rsqrtf(fmaxf((float)in_cnt[t >> 5], 1.0f));
    }
}

__global__ void degree_kernel(const int* __restrict__ src, const int* __restrict__ dst,
                              int* __restrict__ out_cnt, int* __restrict__ in_cnt,
                              int n_edges) {
    int i = blockIdx.x * blockDim.x + threadIdx.x;
    if (i < n_edges) {
        atomicAdd(&out_cnt[src[i]], 1);
        atomicAdd(&in_cnt[dst[i]], 1);
    }
}

extern "C" void kernel_launch(void* const* d_in, const int* in_sizes, int n_in,
                              void* d_out, int out_size, void* d_ws, size_t ws_size,
                              hipStream_t stream) {
    const float* feat   = (const float*)d_in[0];
    const int*   src    = (const int*)d_in[1];
    const int*   dst    = (const int*)d_in[2];
    const float* weight = (const float*)d_in[3];
    float*       out    = (float*)d_out;

    int n_nodes = in_sizes[0] / IN_F;   // 100000
    int n_edges = in_sizes[1];          // 1600000
    int n_buckets = (n_nodes + R_NODES - 1) / R_NODES;  // 782 (<= MAXNB)

    // ws layout: [out_cnt n][in_cnt n][gcur MAXNB][ovf_cnt 8][ovf 2*CAP][bkt][tmp][deg n]
    int*      out_cnt = (int*)d_ws;
    int*      in_cnt  = out_cnt + n_nodes;
    int*      gcur    = in_cnt + n_nodes;
    int*      ovf_cnt = gcur + MAXNB;
    int*      ovf     = ovf_cnt + 8;
    unsigned* bkt     = (unsigned*)(ovf + 2 * OVF_CAP);
    float*    tmp     = (float*)(bkt + (size_t)n_buckets * BKT_CAP);
    int*      deg     = (int*)(tmp + (size_t)n_nodes * OUT_F);
    size_t    needed  = (char*)(deg + n_nodes) - (char*)d_ws;

    if (ws_size >= needed && n_buckets <= MAXNB) {
        hipMemsetAsync(out_cnt, 0, ((size_t)2 * n_nodes + MAXNB + 8) * sizeof(int), stream);
        build_kernel<<<(n_edges + EPB - 1) / EPB, 256, 0, stream>>>(
            src, dst, out_cnt, in_cnt, gcur, bkt, ovf, ovf_cnt, n_edges);
        linear_kernel<<<(n_nodes + 127) / 128, 256, 0, stream>>>(
            feat, weight, out_cnt, tmp, n_nodes);
        bucket_gather<<<n_buckets, 1024, 0, stream>>>(
            bkt, gcur, in_cnt, tmp, out, deg, n_nodes);
        ovf_kernel<<<OVF_CAP * 32 / 256, 256, 0, stream>>>(ovf, ovf_cnt, deg, tmp, out);
    } else {
        // fallback: atomic scatter
        float* tmp_fb = (float*)(ovf + 2 * OVF_CAP);
        hipMemsetAsync(out_cnt, 0, ((size_t)2 * n_nodes + MAXNB + 8) * sizeof(int), stream);
        hipMemsetAsync(d_out, 0, (size_t)out_size * sizeof(float), stream);
        degree_kernel<<<(n_edges + 255) / 256, 256, 0, stream>>>(src, dst, out_cnt, in_cnt, n_edges);
        linear_kernel<<<(n_nodes + 127) / 128, 256, 0, stream>>>(feat, weight, out_cnt, tmp_fb, n_nodes);
        long long st = (long long)n_edges * OUT_F;
        scatter_kernel<<<(int)((st + 255) / 256), 256, 0, stream>>>(src, dst, tmp_fb, out, n_edges);
        finalize_kernel<<<(n_nodes * OUT_F + 255) / 256, 256, 0, stream>>>(out, in_cnt, n_nodes * OUT_F);
    }
}